// Round 14
// baseline (98.829 us; speedup 1.0000x reference)
//
#include <hip/hip_runtime.h>
#include <hip/hip_bf16.h>

// UnivariateFlowMixture: N=1e6 points, C=8 channels, L=8 layers, B=32 bins.
// Pipeline: build_tables (1 blk) -> grid_eval (1 thread/grid point, LDS f16
// neighbor exchange, packed 64B rows) -> interp8 (8 lanes per point: wave
// touches 8 cache lines not 64; zero LDS; per-wave private worklist, no
// atomics) -> exact (512 blocks, one lane per flagged (point,channel) pair).
// Round 14: kills interp's gather divergence (the dominant cost since r5).

#define TB 3.0f
#define NB 32
#define NC 8
#define NL 8
#define LN2 0.69314718055994530942f

#define GX0 -6.5f
#define GX1 6.5f
#define TZ 0.5f
#define TL 0.5f

#define PT_FLOATS (64 * 99)                  // 6336: 64 tables of 33|33|33
#define GP_FLOATS (PT_FLOATS + 72 + 72 + 8)  // + Sc | Bb | LJ  (6488 floats)
#define GP_BYTES  (GP_FLOATS * 4)            // 25952
#define TAB_OFF   26112                      // 64B-aligned (64*408)

__device__ __forceinline__ float softplusf(float v) {
    return fmaxf(v, 0.f) + log1pf(expf(-fabsf(v)));
}

__device__ __forceinline__ unsigned short f2h(float f) {
    _Float16 h = (_Float16)f;
    unsigned short u;
    __builtin_memcpy(&u, &h, 2);
    return u;
}
__device__ __forceinline__ float h2f(unsigned short u) {
    _Float16 h;
    __builtin_memcpy(&h, &u, 2);
    return (float)h;
}

__device__ __forceinline__ int bsearch32(const float* __restrict__ E, float xc) {
    int i = (xc >= E[16]) ? 16 : 0;
    i += (xc >= E[i + 8]) ? 8 : 0;
    i += (xc >= E[i + 4]) ? 4 : 0;
    i += (xc >= E[i + 2]) ? 2 : 0;
    i += (xc >= E[i + 1]) ? 1 : 0;
    return i;
}

// Tlc: [0..32] cumw edges, [33..65] cumh, [66..98] derivs (LDS or global)
__device__ __forceinline__ void spline_eval(const float* __restrict__ Tlc,
                                            float zc, float& zo, float& ldo) {
    const float* E  = Tlc;
    const float* Hc = Tlc + 33;
    const float* Dv = Tlc + 66;

    float xc = fminf(fmaxf(zc, -TB), TB);
    int i = bsearch32(E, xc);

    float xk  = E[i],  xk1 = E[i + 1];
    float yk  = Hc[i], yk1 = Hc[i + 1];
    float dk  = Dv[i], dk1 = Dv[i + 1];

    float wk    = xk1 - xk;
    float hk    = yk1 - yk;
    float invw  = __builtin_amdgcn_rcpf(wk);
    float delta = hk * invw;
    float th    = (xc - xk) * invw;
    float omt   = 1.f - th;
    float t1m   = th * omt;
    float th2   = th * th;

    float num    = hk * fmaf(delta, th2, dk * t1m);
    float den    = fmaf(fmaf(-2.f, delta, dk + dk1), t1m, delta);
    float invden = __builtin_amdgcn_rcpf(den);
    float y      = fmaf(num, invden, yk);

    float dt    = delta * t1m;
    float inner = fmaf(dk1, th2, fmaf(dk, omt * omt, dt + dt));
    float dnum  = (delta * delta) * inner;
    float r  = dnum * invden * invden;
    float ld = LN2 * __builtin_amdgcn_logf(r);

    bool inside = (zc >= -TB) && (zc <= TB);
    zo  = inside ? y : zc;
    ldo = inside ? ld : 0.f;
}

// exact chain for one (x, channel) from table block T (LDS)
__device__ __forceinline__ void exact_chain(const float* __restrict__ T,
                                            float xv, int c,
                                            float& zout, float& lout) {
    const float* ScT = T + PT_FLOATS;
    const float* BbT = ScT + 72;
    const float* LJT = BbT + 72;
    float zc = xv;
    float lacc = LJT[c];
#pragma unroll 1
    for (int l = 0; l < NL; ++l) {
        zc = (zc - BbT[l * 8 + c]) * ScT[l * 8 + c];
        float ld;
        spline_eval(T + (l * 8 + c) * 99, zc, zc, ld);
        lacc += ld;
    }
    zout = (zc - BbT[NL * 8 + c]) * ScT[NL * 8 + c];
    lout = lacc;
}

// ---------------- kernel 1: build tables once -> gparam ----------------
extern "C" __global__ void __launch_bounds__(256)
build_tables(const float* __restrict__ w, const float* __restrict__ h,
             const float* __restrict__ s, const float* __restrict__ bias,
             const float* __restrict__ lsc, float* __restrict__ gparam)
{
    __shared__ float T[PT_FLOATS];
    __shared__ float Sc[72], Bb[72], LJ[8];

    const int tid = threadIdx.x;

    if (tid < 64) {                       // widths -> cumw edges
        const int l = tid >> 3, c = tid & 7;
        float* cw = &T[tid * 99];
        const float* wr = w + (l * NC + c) * NB;
        float m = wr[0];
        for (int b = 1; b < NB; ++b) m = fmaxf(m, wr[b]);
        float sum = 0.f;
        for (int b = 0; b < NB; ++b) sum += expf(wr[b] - m);
        float inv = 1.f / sum;
        float acc = 0.f;
        cw[0] = -TB;
        for (int b = 0; b < NB; ++b) {
            acc += 1e-3f + (1.f - 1e-3f * NB) * (expf(wr[b] - m) * inv);
            cw[b + 1] = 6.f * acc - 3.f;
        }
        cw[NB] = TB;
    } else if (tid < 128) {               // heights -> cumh
        const int t = tid - 64;
        float* ch = &T[t * 99 + 33];
        const int l = t >> 3, c = t & 7;
        const float* hr = h + (l * NC + c) * NB;
        float m = hr[0];
        for (int b = 1; b < NB; ++b) m = fmaxf(m, hr[b]);
        float sum = 0.f;
        for (int b = 0; b < NB; ++b) sum += expf(hr[b] - m);
        float inv = 1.f / sum;
        float acc = 0.f;
        ch[0] = -TB;
        for (int b = 0; b < NB; ++b) {
            acc += 1e-3f + (1.f - 1e-3f * NB) * (expf(hr[b] - m) * inv);
            ch[b + 1] = 6.f * acc - 3.f;
        }
        ch[NB] = TB;
    } else if (tid < 192) {               // derivs
        const int t = tid - 128;
        const int l = t >> 3, c = t & 7;
        float* dv = &T[t * 99 + 66];
        const float* sr = s + (l * NC + c) * (NB - 1);
        const float cst = logf(expm1f(1.f - 1e-3f));
        const float dbound = 1e-3f + softplusf(cst);
        dv[0]  = dbound;
        dv[NB] = dbound;
        for (int k = 0; k < NB - 1; ++k)
            dv[k + 1] = 1e-3f + softplusf(sr[k]);
    }
    if (tid < 72) { Sc[tid] = expf(-lsc[tid]); Bb[tid] = bias[tid]; }
    if (tid < 8) {
        float a = 0.f;
        for (int l = 0; l <= NL; ++l) a += lsc[l * NC + tid];
        LJ[tid] = -a;
    }
    __syncthreads();

    for (int k = tid; k < PT_FLOATS; k += 256) gparam[k] = T[k];
    if (tid < 72) gparam[PT_FLOATS + tid]       = Sc[tid];
    if (tid < 72) gparam[PT_FLOATS + 72 + tid]  = Bb[tid];
    if (tid < 8)  gparam[PT_FLOATS + 144 + tid] = LJ[tid];
}

// ------- kernel 2: grid eval, 1 thread per grid point (8 ch serial) --------
// Block covers 256 points with 1 overlap: rows [b*255, b*255+254] written.
extern "C" __global__ void __launch_bounds__(256)
grid_eval(const float* __restrict__ gparam, char* __restrict__ tabb,
          int G, float dx)
{
    __shared__ float T[GP_FLOATS];
    __shared__ unsigned short ZL[256 * 16];   // h(z)[8] | h(lj)[8] per thread
    for (int k = threadIdx.x; k < GP_FLOATS; k += 256) T[k] = gparam[k];
    __syncthreads();
    const float* ScT = T + PT_FLOATS;
    const float* BbT = ScT + 72;
    const float* LJT = BbT + 72;

    const int t  = threadIdx.x;
    const int p0 = blockIdx.x * 255;
    const int i  = min(p0 + t, G - 1);

    const float xv = fmaf((float)i, dx, GX0);
    float z[NC], lj[NC];
#pragma unroll
    for (int c = 0; c < NC; ++c) { z[c] = xv; lj[c] = LJT[c]; }

#pragma unroll 1
    for (int l = 0; l < NL; ++l) {
        const float* Tl = T + l * NC * 99;
#pragma unroll
        for (int c = 0; c < NC; ++c) {
            float u = (z[c] - BbT[l * 8 + c]) * ScT[l * 8 + c];
            float zo, ld;
            spline_eval(Tl + c * 99, u, zo, ld);
            z[c] = zo;
            lj[c] += ld;
        }
    }
    unsigned short zh[NC], lh[NC];
#pragma unroll
    for (int c = 0; c < NC; ++c) {
        z[c] = (z[c] - BbT[NL * 8 + c]) * ScT[NL * 8 + c];
        zh[c] = f2h(z[c]);
        lh[c] = f2h(lj[c]);
        ZL[t * 16 + c]     = zh[c];
        ZL[t * 16 + 8 + c] = lh[c];
    }
    __syncthreads();

    const int r = p0 + t;
    if (t < 255 && r <= G - 2) {
        ushort4* rowp = (ushort4*)(tabb + (size_t)r * 64);
#pragma unroll
        for (int c = 0; c < NC; ++c) {
            const float zn  = h2f(ZL[(t + 1) * 16 + c]);
            const float ljn = h2f(ZL[(t + 1) * 16 + 8 + c]);
            ushort4 v;
            v.x = zh[c]; v.y = f2h(zn - h2f(zh[c]));
            v.z = lh[c]; v.w = f2h(ljn - h2f(lh[c]));
            rowp[c] = v;
        }
    }
}

// ------- kernel 3: interp, 8 lanes per point (coalesced row gather) ---------
// thread = (point p, channel c); wave = 8 points x 8 channels.
// Flagged pairs -> per-wave private worklist region (no atomics).
extern "C" __global__ void __launch_bounds__(256)
interp_kernel(const float* __restrict__ x, const char* __restrict__ tabb,
              float* __restrict__ out,
              unsigned* __restrict__ wcnt, unsigned* __restrict__ wl,
              int N, int G, float dx, float invdx)
{
    const int gt   = blockIdx.x * 256 + threadIdx.x;
    const int p    = gt >> 3;             // point id
    const int c    = gt & 7;              // channel
    const int lane = threadIdx.x & 63;
    const int wid  = gt >> 6;             // global wave id = region id
    const bool active = (p < N);

    float zv = 0.f, lv = 0.f;
    bool flag = false;
    float xv = 0.f;
    if (active) {
        xv = x[p];                        // 8 lanes same addr -> broadcast
        int i = (int)floorf((xv - GX0) * invdx);
        const bool oor = !(xv > GX0 && xv < GX1);
        i = min(max(i, 0), G - 2);
        const float t = (xv - fmaf((float)i, dx, GX0)) * invdx;

        // one 8B chunk of the 64B row: 8-lane group covers the row contiguously
        const uint2 ab = *(const uint2*)(tabb + (size_t)i * 64 + c * 8);
        const float z0 = h2f((unsigned short)ab.x);
        const float dz = h2f((unsigned short)(ab.x >> 16));
        const float l0 = h2f((unsigned short)ab.y);
        const float dl = h2f((unsigned short)(ab.y >> 16));
        zv = fmaf(t, dz, z0);
        lv = fmaf(t, dl, l0);
        flag = oor || (fabsf(dz) > TZ) || (fabsf(dl) > TL);
    }

    // per-wave private region compaction (zero atomics, deterministic)
    const unsigned long long m = __ballot(flag);
    if (flag) {
        const int rank = __popcll(m & ((1ull << lane) - 1ull));
        wl[(size_t)wid * 64 + rank] = ((unsigned)p << 3) | (unsigned)c;
    }
    if (lane == 0)                        // lane 0 active for every W < nwl
        wcnt[wid] = (unsigned)__popcll(m);

    if (active) {
        out[(size_t)p * NC + c] = zv;                      // 256B/wave contig
        out[(size_t)N * NC + (size_t)p * NC + c] = lv;
    }
}

// ------- kernel 4: exact pass, one lane per flagged (point,channel) ---------
extern "C" __global__ void __launch_bounds__(256)
exact_kernel(const float* __restrict__ x, const float* __restrict__ gparam,
             const unsigned* __restrict__ wcnt, const unsigned* __restrict__ wl,
             int nwl, float* __restrict__ out, int N)
{
    __shared__ float T[GP_FLOATS];
    for (int k = threadIdx.x; k < GP_FLOATS; k += 256) T[k] = gparam[k];
    __syncthreads();

    const int lane = threadIdx.x & 63;
    const int wloc = threadIdx.x >> 6;    // 0..3
    for (int W = blockIdx.x * 4 + wloc; W < nwl; W += (int)gridDim.x * 4) {
        const unsigned cnt = min(wcnt[W], 64u);
        if (lane < (int)cnt) {
            const unsigned ent = wl[(size_t)W * 64 + lane];
            const int n = (int)(ent >> 3);
            const int c = (int)(ent & 7u);
            if (n < N) {                  // defensive
                float zo, lo;
                exact_chain(T, x[n], c, zo, lo);
                out[(size_t)n * NC + c] = zo;
                out[(size_t)N * NC + (size_t)n * NC + c] = lo;
            }
        }
    }
}

// ---------------- legacy monolithic kernel (ws-too-small fallback) ----------
extern "C" __global__ void __launch_bounds__(256)
flow_kernel(const float* __restrict__ x, const float* __restrict__ w,
            const float* __restrict__ h, const float* __restrict__ s,
            const float* __restrict__ bias, const float* __restrict__ lsc,
            float* __restrict__ out, int N)
{
    __shared__ float T[PT_FLOATS];
    __shared__ float Bb[NL + 1][NC];
    __shared__ float Sc[NL + 1][NC];
    __shared__ float LJC[NC];

    const int tid = threadIdx.x;
    if (tid < 64) {
        const int l = tid >> 3, c = tid & 7;
        float* cw = &T[tid * 99];
        {
            const float* wr = w + (l * NC + c) * NB;
            float m = wr[0];
            for (int b = 1; b < NB; ++b) m = fmaxf(m, wr[b]);
            float sum = 0.f;
            for (int b = 0; b < NB; ++b) sum += expf(wr[b] - m);
            float inv = 1.f / sum;
            float acc = 0.f;
            cw[0] = -TB;
            for (int b = 0; b < NB; ++b) {
                acc += 1e-3f + (1.f - 1e-3f * NB) * (expf(wr[b] - m) * inv);
                cw[b + 1] = 6.f * acc - 3.f;
            }
            cw[NB] = TB;
        }
        {
            float* ch = cw + 33;
            const float* hr = h + (l * NC + c) * NB;
            float m = hr[0];
            for (int b = 1; b < NB; ++b) m = fmaxf(m, hr[b]);
            float sum = 0.f;
            for (int b = 0; b < NB; ++b) sum += expf(hr[b] - m);
            float inv = 1.f / sum;
            float acc = 0.f;
            ch[0] = -TB;
            for (int b = 0; b < NB; ++b) {
                acc += 1e-3f + (1.f - 1e-3f * NB) * (expf(hr[b] - m) * inv);
                ch[b + 1] = 6.f * acc - 3.f;
            }
            ch[NB] = TB;
        }
        {
            float* dv = cw + 66;
            const float* sr = s + (l * NC + c) * (NB - 1);
            const float cst = logf(expm1f(1.f - 1e-3f));
            const float dbound = 1e-3f + softplusf(cst);
            dv[0]  = dbound;
            dv[NB] = dbound;
            for (int k = 0; k < NB - 1; ++k)
                dv[k + 1] = 1e-3f + softplusf(sr[k]);
        }
    }
    if (tid < (NL + 1) * NC) {
        const int l = tid >> 3, c = tid & 7;
        Bb[l][c] = bias[tid];
        Sc[l][c] = expf(-lsc[tid]);
    }
    if (tid < NC) {
        float a = 0.f;
        for (int l = 0; l <= NL; ++l) a += lsc[l * NC + tid];
        LJC[tid] = -a;
    }
    __syncthreads();

    const int n = blockIdx.x * 256 + tid;
    if (n >= N) return;
    const float xv = x[n];
    float z[NC], lj[NC];
#pragma unroll
    for (int c = 0; c < NC; ++c) { z[c] = xv; lj[c] = LJC[c]; }
#pragma unroll 1
    for (int l = 0; l < NL; ++l) {
        const float* Tl = &T[l * NC * 99];
#pragma unroll
        for (int c = 0; c < NC; ++c) {
            float zc = (z[c] - Bb[l][c]) * Sc[l][c];
            float zo, ld;
            spline_eval(Tl + c * 99, zc, zo, ld);
            z[c] = zo;
            lj[c] += ld;
        }
    }
#pragma unroll
    for (int c = 0; c < NC; ++c) z[c] = (z[c] - Bb[NL][c]) * Sc[NL][c];

    float4* oz = (float4*)(out + (size_t)n * NC);
    oz[0] = make_float4(z[0], z[1], z[2], z[3]);
    oz[1] = make_float4(z[4], z[5], z[6], z[7]);
    float4* ol = (float4*)(out + (size_t)N * NC + (size_t)n * NC);
    ol[0] = make_float4(lj[0], lj[1], lj[2], lj[3]);
    ol[1] = make_float4(lj[4], lj[5], lj[6], lj[7]);
}

extern "C" void kernel_launch(void* const* d_in, const int* in_sizes, int n_in,
                              void* d_out, int out_size, void* d_ws, size_t ws_size,
                              hipStream_t stream) {
    const float* x    = (const float*)d_in[0];
    const float* w    = (const float*)d_in[1];
    const float* h    = (const float*)d_in[2];
    const float* s    = (const float*)d_in[3];
    const float* bias = (const float*)d_in[4];
    const float* lsc  = (const float*)d_in[5];
    float* out = (float*)d_out;
    const int N = in_sizes[0];

    const int nwl = (N + 7) / 8;          // one region per 8-point wave
    // Layout (bytes): [0,GP_BYTES) gparam | [TAB_OFF,+G*64) tab |
    //   [tabEnd,+nwl*4) wcnt | [.., +nwl*256) wl
    int G = 65536;
    while (G > 2048 &&
           ((size_t)TAB_OFF + (size_t)G * 64 + (size_t)nwl * 260) > ws_size)
        G >>= 1;
    const size_t tabEnd = (size_t)TAB_OFF + (size_t)G * 64;
    const size_t need   = tabEnd + (size_t)nwl * 260;

    if (need <= ws_size) {
        char* basep = (char*)d_ws;
        float*    gparam = (float*)basep;
        char*     tabb   = basep + TAB_OFF;
        unsigned* wcnt   = (unsigned*)(basep + tabEnd);
        unsigned* wl     = (unsigned*)(basep + tabEnd + (size_t)nwl * 4);

        const float dx = (GX1 - GX0) / (float)(G - 1);
        const int gblocks = (G - 1 + 254) / 255;
        const int iblocks = (int)(((long long)N * 8 + 255) / 256);
        build_tables<<<1, 256, 0, stream>>>(w, h, s, bias, lsc, gparam);
        grid_eval<<<gblocks, 256, 0, stream>>>(gparam, tabb, G, dx);
        interp_kernel<<<iblocks, 256, 0, stream>>>(
            x, tabb, out, wcnt, wl, N, G, dx, 1.f / dx);
        exact_kernel<<<512, 256, 0, stream>>>(
            x, gparam, wcnt, wl, nwl, out, N);
    } else {
        flow_kernel<<<(N + 255) / 256, 256, 0, stream>>>(
            x, w, h, s, bias, lsc, out, N);
    }
}

// Round 15
// 74.613 us; speedup vs baseline: 1.3245x; 1.3245x over previous
//
#include <hip/hip_runtime.h>
#include <hip/hip_bf16.h>

// UnivariateFlowMixture: N=1e6 points, C=8 channels, L=8 layers, B=32 bins.
// Pipeline: build_tables (1 blk) -> grid_eval (1 thread/grid point, LDS f16
// neighbor exchange, packed 64B rows) -> interp_fused8 (8 lanes per point,
// coalesced row gather, block pair pool + in-kernel exact, zero atomics).
// Round 15: r13's fused structure + r14's 8-lane gather (8 lines/wave, not
// 64); r14's separate exact kernel (45us region scan) eliminated again.

#define TB 3.0f
#define NB 32
#define NC 8
#define NL 8
#define LN2 0.69314718055994530942f

#define GX0 -6.5f
#define GX1 6.5f
#define TZ 0.5f
#define TL 0.5f

#define PT_FLOATS (64 * 99)                  // 6336: 64 tables of 33|33|33
#define GP_FLOATS (PT_FLOATS + 72 + 72 + 8)  // + Sc | Bb | LJ  (6488 floats)
#define GP_BYTES  (GP_FLOATS * 4)            // 25952
#define TAB_OFF   26112                      // 64B-aligned (64*408)
#define CAP 256                              // pair pool per block

__device__ __forceinline__ float softplusf(float v) {
    return fmaxf(v, 0.f) + log1pf(expf(-fabsf(v)));
}

__device__ __forceinline__ unsigned short f2h(float f) {
    _Float16 h = (_Float16)f;
    unsigned short u;
    __builtin_memcpy(&u, &h, 2);
    return u;
}
__device__ __forceinline__ float h2f(unsigned short u) {
    _Float16 h;
    __builtin_memcpy(&h, &u, 2);
    return (float)h;
}

__device__ __forceinline__ int bsearch32(const float* __restrict__ E, float xc) {
    int i = (xc >= E[16]) ? 16 : 0;
    i += (xc >= E[i + 8]) ? 8 : 0;
    i += (xc >= E[i + 4]) ? 4 : 0;
    i += (xc >= E[i + 2]) ? 2 : 0;
    i += (xc >= E[i + 1]) ? 1 : 0;
    return i;
}

// Tlc: [0..32] cumw edges, [33..65] cumh, [66..98] derivs (LDS or global)
__device__ __forceinline__ void spline_eval(const float* __restrict__ Tlc,
                                            float zc, float& zo, float& ldo) {
    const float* E  = Tlc;
    const float* Hc = Tlc + 33;
    const float* Dv = Tlc + 66;

    float xc = fminf(fmaxf(zc, -TB), TB);
    int i = bsearch32(E, xc);

    float xk  = E[i],  xk1 = E[i + 1];
    float yk  = Hc[i], yk1 = Hc[i + 1];
    float dk  = Dv[i], dk1 = Dv[i + 1];

    float wk    = xk1 - xk;
    float hk    = yk1 - yk;
    float invw  = __builtin_amdgcn_rcpf(wk);
    float delta = hk * invw;
    float th    = (xc - xk) * invw;
    float omt   = 1.f - th;
    float t1m   = th * omt;
    float th2   = th * th;

    float num    = hk * fmaf(delta, th2, dk * t1m);
    float den    = fmaf(fmaf(-2.f, delta, dk + dk1), t1m, delta);
    float invden = __builtin_amdgcn_rcpf(den);
    float y      = fmaf(num, invden, yk);

    float dt    = delta * t1m;
    float inner = fmaf(dk1, th2, fmaf(dk, omt * omt, dt + dt));
    float dnum  = (delta * delta) * inner;
    float r  = dnum * invden * invden;
    float ld = LN2 * __builtin_amdgcn_logf(r);

    bool inside = (zc >= -TB) && (zc <= TB);
    zo  = inside ? y : zc;
    ldo = inside ? ld : 0.f;
}

// exact chain for one (x, channel) from LDS-staged T
__device__ __forceinline__ void exact_chain(const float* __restrict__ T,
                                            float xv, int c,
                                            float& zout, float& lout) {
    const float* ScT = T + PT_FLOATS;
    const float* BbT = ScT + 72;
    const float* LJT = BbT + 72;
    float zc = xv;
    float lacc = LJT[c];
#pragma unroll 1
    for (int l = 0; l < NL; ++l) {
        zc = (zc - BbT[l * 8 + c]) * ScT[l * 8 + c];
        float ld;
        spline_eval(T + (l * 8 + c) * 99, zc, zc, ld);
        lacc += ld;
    }
    zout = (zc - BbT[NL * 8 + c]) * ScT[NL * 8 + c];
    lout = lacc;
}

// ---------------- kernel 1: build tables once -> gparam ----------------
extern "C" __global__ void __launch_bounds__(256)
build_tables(const float* __restrict__ w, const float* __restrict__ h,
             const float* __restrict__ s, const float* __restrict__ bias,
             const float* __restrict__ lsc, float* __restrict__ gparam)
{
    __shared__ float T[PT_FLOATS];
    __shared__ float Sc[72], Bb[72], LJ[8];

    const int tid = threadIdx.x;

    if (tid < 64) {                       // widths -> cumw edges
        const int l = tid >> 3, c = tid & 7;
        float* cw = &T[tid * 99];
        const float* wr = w + (l * NC + c) * NB;
        float m = wr[0];
        for (int b = 1; b < NB; ++b) m = fmaxf(m, wr[b]);
        float sum = 0.f;
        for (int b = 0; b < NB; ++b) sum += expf(wr[b] - m);
        float inv = 1.f / sum;
        float acc = 0.f;
        cw[0] = -TB;
        for (int b = 0; b < NB; ++b) {
            acc += 1e-3f + (1.f - 1e-3f * NB) * (expf(wr[b] - m) * inv);
            cw[b + 1] = 6.f * acc - 3.f;
        }
        cw[NB] = TB;
    } else if (tid < 128) {               // heights -> cumh
        const int t = tid - 64;
        float* ch = &T[t * 99 + 33];
        const int l = t >> 3, c = t & 7;
        const float* hr = h + (l * NC + c) * NB;
        float m = hr[0];
        for (int b = 1; b < NB; ++b) m = fmaxf(m, hr[b]);
        float sum = 0.f;
        for (int b = 0; b < NB; ++b) sum += expf(hr[b] - m);
        float inv = 1.f / sum;
        float acc = 0.f;
        ch[0] = -TB;
        for (int b = 0; b < NB; ++b) {
            acc += 1e-3f + (1.f - 1e-3f * NB) * (expf(hr[b] - m) * inv);
            ch[b + 1] = 6.f * acc - 3.f;
        }
        ch[NB] = TB;
    } else if (tid < 192) {               // derivs
        const int t = tid - 128;
        const int l = t >> 3, c = t & 7;
        float* dv = &T[t * 99 + 66];
        const float* sr = s + (l * NC + c) * (NB - 1);
        const float cst = logf(expm1f(1.f - 1e-3f));
        const float dbound = 1e-3f + softplusf(cst);
        dv[0]  = dbound;
        dv[NB] = dbound;
        for (int k = 0; k < NB - 1; ++k)
            dv[k + 1] = 1e-3f + softplusf(sr[k]);
    }
    if (tid < 72) { Sc[tid] = expf(-lsc[tid]); Bb[tid] = bias[tid]; }
    if (tid < 8) {
        float a = 0.f;
        for (int l = 0; l <= NL; ++l) a += lsc[l * NC + tid];
        LJ[tid] = -a;
    }
    __syncthreads();

    for (int k = tid; k < PT_FLOATS; k += 256) gparam[k] = T[k];
    if (tid < 72) gparam[PT_FLOATS + tid]       = Sc[tid];
    if (tid < 72) gparam[PT_FLOATS + 72 + tid]  = Bb[tid];
    if (tid < 8)  gparam[PT_FLOATS + 144 + tid] = LJ[tid];
}

// ------- kernel 2: grid eval, 1 thread per grid point (8 ch serial) --------
// Block covers 256 points with 1 overlap: rows [b*255, b*255+254] written.
extern "C" __global__ void __launch_bounds__(256)
grid_eval(const float* __restrict__ gparam, char* __restrict__ tabb,
          int G, float dx)
{
    __shared__ float T[GP_FLOATS];
    __shared__ unsigned short ZL[256 * 16];   // h(z)[8] | h(lj)[8] per thread
    for (int k = threadIdx.x; k < GP_FLOATS; k += 256) T[k] = gparam[k];
    __syncthreads();
    const float* ScT = T + PT_FLOATS;
    const float* BbT = ScT + 72;
    const float* LJT = BbT + 72;

    const int t  = threadIdx.x;
    const int p0 = blockIdx.x * 255;
    const int i  = min(p0 + t, G - 1);

    const float xv = fmaf((float)i, dx, GX0);
    float z[NC], lj[NC];
#pragma unroll
    for (int c = 0; c < NC; ++c) { z[c] = xv; lj[c] = LJT[c]; }

#pragma unroll 1
    for (int l = 0; l < NL; ++l) {
        const float* Tl = T + l * NC * 99;
#pragma unroll
        for (int c = 0; c < NC; ++c) {
            float u = (z[c] - BbT[l * 8 + c]) * ScT[l * 8 + c];
            float zo, ld;
            spline_eval(Tl + c * 99, u, zo, ld);
            z[c] = zo;
            lj[c] += ld;
        }
    }
    unsigned short zh[NC], lh[NC];
#pragma unroll
    for (int c = 0; c < NC; ++c) {
        z[c] = (z[c] - BbT[NL * 8 + c]) * ScT[NL * 8 + c];
        zh[c] = f2h(z[c]);
        lh[c] = f2h(lj[c]);
        ZL[t * 16 + c]     = zh[c];
        ZL[t * 16 + 8 + c] = lh[c];
    }
    __syncthreads();

    const int r = p0 + t;
    if (t < 255 && r <= G - 2) {
        ushort4* rowp = (ushort4*)(tabb + (size_t)r * 64);
#pragma unroll
        for (int c = 0; c < NC; ++c) {
            const float zn  = h2f(ZL[(t + 1) * 16 + c]);
            const float ljn = h2f(ZL[(t + 1) * 16 + 8 + c]);
            ushort4 v;
            v.x = zh[c]; v.y = f2h(zn - h2f(zh[c]));
            v.z = lh[c]; v.w = f2h(ljn - h2f(lh[c]));
            rowp[c] = v;
        }
    }
}

// ------- kernel 3: fused interp, 8 lanes/point + in-block exact -------------
// Block covers 256 points. Thread = (pbase=tid>>3, c=tid&7); loop g=0..7 over
// point groups: p_local = g*32+pbase. Wave-g reads 8 random 64B rows as
// contiguous 8B chunks (8 cache lines/instr). Deterministic pool, no atomics.
extern "C" __global__ void __launch_bounds__(256)
interp_kernel(const float* __restrict__ x, const char* __restrict__ tabb,
              const float* __restrict__ gparam, float* __restrict__ out,
              int N, int G, float dx, float invdx)
{
    __shared__ float T[GP_FLOATS];
    __shared__ float xbuf[256];
    __shared__ unsigned short pool[CAP];
    __shared__ float resZ[CAP], resL[CAP];
    __shared__ unsigned wgcnt[8][4];

    const int tid   = threadIdx.x;
    const int c     = tid & 7;
    const int pbase = tid >> 3;           // 0..31
    const int lane  = tid & 63;
    const int wloc  = tid >> 6;           // 0..3
    const int P0    = blockIdx.x * 256;

    float zv[8], lv[8], xr[8];
    unsigned long long mg[8];
    unsigned char myf[8];

#pragma unroll
    for (int g = 0; g < 8; ++g) {
        const int pl = g * 32 + pbase;
        const int p  = P0 + pl;
        const bool active = (p < N);
        float xv = 0.f, z0 = 0.f, dz = 0.f, l0 = 0.f, dl = 0.f;
        bool flag = false;
        float t = 0.f;
        if (active) {
            xv = x[p];                    // 8 lanes same addr -> broadcast
            int i = (int)floorf((xv - GX0) * invdx);
            const bool oor = !(xv > GX0 && xv < GX1);
            i = min(max(i, 0), G - 2);
            t = (xv - fmaf((float)i, dx, GX0)) * invdx;
            const uint2 ab = *(const uint2*)(tabb + (size_t)i * 64 + c * 8);
            z0 = h2f((unsigned short)ab.x);
            dz = h2f((unsigned short)(ab.x >> 16));
            l0 = h2f((unsigned short)ab.y);
            dl = h2f((unsigned short)(ab.y >> 16));
            flag = oor || (fabsf(dz) > TZ) || (fabsf(dl) > TL);
        }
        zv[g] = fmaf(t, dz, z0);
        lv[g] = fmaf(t, dl, l0);
        xr[g] = xv;
        myf[g] = flag ? 1 : 0;
        mg[g] = __ballot(flag);
        if (lane == 0) wgcnt[g][wloc] = (unsigned)__popcll(mg[g]);
        if (c == 0) xbuf[pl] = xv;        // one writer per point
    }
    __syncthreads();                      // wgcnt + xbuf visible

    // offsets: pairs ordered by (g, wave, lane-rank); btot = total
    unsigned btot = 0;
    unsigned goff[8];
#pragma unroll
    for (int g = 0; g < 8; ++g) {
        unsigned og = btot;               // sum of all previous g totals
        unsigned wo = 0;
#pragma unroll
        for (int j = 0; j < 4; ++j) {
            const unsigned v = wgcnt[g][j];
            if (j < wloc) wo += v;
            btot += v;
        }
        goff[g] = og + wo;
    }

    const unsigned long long lowmask = (1ull << lane) - 1ull;
#pragma unroll
    for (int g = 0; g < 8; ++g) {
        if (myf[g]) {
            const unsigned idx = goff[g] + (unsigned)__popcll(mg[g] & lowmask);
            if (idx < CAP)
                pool[idx] = (unsigned short)(((g * 32 + pbase) << 3) | c);
        }
    }
    if (btot > 0) {                       // stage tables only when needed
        for (int k = tid; k < GP_FLOATS; k += 256) T[k] = gparam[k];
    }
    __syncthreads();                      // pool + T visible

    const unsigned pcnt = min(btot, (unsigned)CAP);
    for (unsigned k = tid; k < pcnt; k += 256) {
        const unsigned pr = pool[k];
        float zo, lo;
        exact_chain(T, xbuf[pr >> 3], (int)(pr & 7u), zo, lo);
        resZ[k] = zo; resL[k] = lo;
    }
    __syncthreads();                      // results visible

#pragma unroll
    for (int g = 0; g < 8; ++g) {
        if (myf[g]) {
            const unsigned idx = goff[g] + (unsigned)__popcll(mg[g] & lowmask);
            if (idx < CAP) {
                zv[g] = resZ[idx]; lv[g] = resL[idx];
            } else {                      // pool overflow: inline exact
                exact_chain(T, xr[g], c, zv[g], lv[g]);
            }
        }
    }

#pragma unroll
    for (int g = 0; g < 8; ++g) {
        const int pl = g * 32 + pbase;
        const int p  = P0 + pl;
        if (p < N) {
            out[(size_t)p * NC + c] = zv[g];                 // 256B/wave contig
            out[(size_t)N * NC + (size_t)p * NC + c] = lv[g];
        }
    }
}

// ---------------- legacy monolithic kernel (ws-too-small fallback) ----------
extern "C" __global__ void __launch_bounds__(256)
flow_kernel(const float* __restrict__ x, const float* __restrict__ w,
            const float* __restrict__ h, const float* __restrict__ s,
            const float* __restrict__ bias, const float* __restrict__ lsc,
            float* __restrict__ out, int N)
{
    __shared__ float T[PT_FLOATS];
    __shared__ float Bb[NL + 1][NC];
    __shared__ float Sc[NL + 1][NC];
    __shared__ float LJC[NC];

    const int tid = threadIdx.x;
    if (tid < 64) {
        const int l = tid >> 3, c = tid & 7;
        float* cw = &T[tid * 99];
        {
            const float* wr = w + (l * NC + c) * NB;
            float m = wr[0];
            for (int b = 1; b < NB; ++b) m = fmaxf(m, wr[b]);
            float sum = 0.f;
            for (int b = 0; b < NB; ++b) sum += expf(wr[b] - m);
            float inv = 1.f / sum;
            float acc = 0.f;
            cw[0] = -TB;
            for (int b = 0; b < NB; ++b) {
                acc += 1e-3f + (1.f - 1e-3f * NB) * (expf(wr[b] - m) * inv);
                cw[b + 1] = 6.f * acc - 3.f;
            }
            cw[NB] = TB;
        }
        {
            float* ch = cw + 33;
            const float* hr = h + (l * NC + c) * NB;
            float m = hr[0];
            for (int b = 1; b < NB; ++b) m = fmaxf(m, hr[b]);
            float sum = 0.f;
            for (int b = 0; b < NB; ++b) sum += expf(hr[b] - m);
            float inv = 1.f / sum;
            float acc = 0.f;
            ch[0] = -TB;
            for (int b = 0; b < NB; ++b) {
                acc += 1e-3f + (1.f - 1e-3f * NB) * (expf(hr[b] - m) * inv);
                ch[b + 1] = 6.f * acc - 3.f;
            }
            ch[NB] = TB;
        }
        {
            float* dv = cw + 66;
            const float* sr = s + (l * NC + c) * (NB - 1);
            const float cst = logf(expm1f(1.f - 1e-3f));
            const float dbound = 1e-3f + softplusf(cst);
            dv[0]  = dbound;
            dv[NB] = dbound;
            for (int k = 0; k < NB - 1; ++k)
                dv[k + 1] = 1e-3f + softplusf(sr[k]);
        }
    }
    if (tid < (NL + 1) * NC) {
        const int l = tid >> 3, c = tid & 7;
        Bb[l][c] = bias[tid];
        Sc[l][c] = expf(-lsc[tid]);
    }
    if (tid < NC) {
        float a = 0.f;
        for (int l = 0; l <= NL; ++l) a += lsc[l * NC + tid];
        LJC[tid] = -a;
    }
    __syncthreads();

    const int n = blockIdx.x * 256 + tid;
    if (n >= N) return;
    const float xv = x[n];
    float z[NC], lj[NC];
#pragma unroll
    for (int c = 0; c < NC; ++c) { z[c] = xv; lj[c] = LJC[c]; }
#pragma unroll 1
    for (int l = 0; l < NL; ++l) {
        const float* Tl = &T[l * NC * 99];
#pragma unroll
        for (int c = 0; c < NC; ++c) {
            float zc = (z[c] - Bb[l][c]) * Sc[l][c];
            float zo, ld;
            spline_eval(Tl + c * 99, zc, zo, ld);
            z[c] = zo;
            lj[c] += ld;
        }
    }
#pragma unroll
    for (int c = 0; c < NC; ++c) z[c] = (z[c] - Bb[NL][c]) * Sc[NL][c];

    float4* oz = (float4*)(out + (size_t)n * NC);
    oz[0] = make_float4(z[0], z[1], z[2], z[3]);
    oz[1] = make_float4(z[4], z[5], z[6], z[7]);
    float4* ol = (float4*)(out + (size_t)N * NC + (size_t)n * NC);
    ol[0] = make_float4(lj[0], lj[1], lj[2], lj[3]);
    ol[1] = make_float4(lj[4], lj[5], lj[6], lj[7]);
}

extern "C" void kernel_launch(void* const* d_in, const int* in_sizes, int n_in,
                              void* d_out, int out_size, void* d_ws, size_t ws_size,
                              hipStream_t stream) {
    const float* x    = (const float*)d_in[0];
    const float* w    = (const float*)d_in[1];
    const float* h    = (const float*)d_in[2];
    const float* s    = (const float*)d_in[3];
    const float* bias = (const float*)d_in[4];
    const float* lsc  = (const float*)d_in[5];
    float* out = (float*)d_out;
    const int N = in_sizes[0];

    // Layout (bytes): [0,GP_BYTES) gparam | [TAB_OFF,+G*64) packed tab
    int G = 65536;
    while (G > 2048 && ((size_t)TAB_OFF + (size_t)G * 64) > ws_size)
        G >>= 1;
    const size_t need = (size_t)TAB_OFF + (size_t)G * 64;

    if (need <= ws_size) {
        char* basep = (char*)d_ws;
        float* gparam = (float*)basep;
        char*  tabb   = basep + TAB_OFF;

        const float dx = (GX1 - GX0) / (float)(G - 1);
        const int gblocks = (G - 1 + 254) / 255;
        build_tables<<<1, 256, 0, stream>>>(w, h, s, bias, lsc, gparam);
        grid_eval<<<gblocks, 256, 0, stream>>>(gparam, tabb, G, dx);
        interp_kernel<<<(N + 255) / 256, 256, 0, stream>>>(
            x, tabb, gparam, out, N, G, dx, 1.f / dx);
    } else {
        flow_kernel<<<(N + 255) / 256, 256, 0, stream>>>(
            x, w, h, s, bias, lsc, out, N);
    }
}

// Round 16
// 73.428 us; speedup vs baseline: 1.3459x; 1.0161x over previous
//
#include <hip/hip_runtime.h>
#include <hip/hip_bf16.h>

// UnivariateFlowMixture: N=1e6 points, C=8 channels, L=8 layers, B=32 bins.
// Pipeline: build_tables (1 blk) -> grid_eval (1 thread/grid point, LDS f16
// neighbor exchange, packed 64B rows) -> interp_fused8 (8 lanes/point,
// ISSUE-ALL-LOADS-FIRST then consume; per-wave pool regions; in-kernel exact).
// Round 16: fixes r15's load->ballot serialization (8 dependent latency
// round-trips/wave). Loop A issues all 8 gathers independently; loop B
// consumes. Unflagged stores inline; pool writes direct to out post-barrier.

#define TB 3.0f
#define NB 32
#define NC 8
#define NL 8
#define LN2 0.69314718055994530942f

#define GX0 -6.5f
#define GX1 6.5f
#define TZ 0.5f
#define TL 0.5f

#define PT_FLOATS (64 * 99)                  // 6336: 64 tables of 33|33|33
#define GP_FLOATS (PT_FLOATS + 72 + 72 + 8)  // + Sc | Bb | LJ  (6488 floats)
#define GP_BYTES  (GP_FLOATS * 4)            // 25952
#define TAB_OFF   26112                      // 64B-aligned (64*408)
#define CAP 256                              // pool: 4 wave-regions x 64

__device__ __forceinline__ float softplusf(float v) {
    return fmaxf(v, 0.f) + log1pf(expf(-fabsf(v)));
}

__device__ __forceinline__ unsigned short f2h(float f) {
    _Float16 h = (_Float16)f;
    unsigned short u;
    __builtin_memcpy(&u, &h, 2);
    return u;
}
__device__ __forceinline__ float h2f(unsigned short u) {
    _Float16 h;
    __builtin_memcpy(&h, &u, 2);
    return (float)h;
}

__device__ __forceinline__ int bsearch32(const float* __restrict__ E, float xc) {
    int i = (xc >= E[16]) ? 16 : 0;
    i += (xc >= E[i + 8]) ? 8 : 0;
    i += (xc >= E[i + 4]) ? 4 : 0;
    i += (xc >= E[i + 2]) ? 2 : 0;
    i += (xc >= E[i + 1]) ? 1 : 0;
    return i;
}

// Tlc: [0..32] cumw edges, [33..65] cumh, [66..98] derivs (LDS or global)
__device__ __forceinline__ void spline_eval(const float* __restrict__ Tlc,
                                            float zc, float& zo, float& ldo) {
    const float* E  = Tlc;
    const float* Hc = Tlc + 33;
    const float* Dv = Tlc + 66;

    float xc = fminf(fmaxf(zc, -TB), TB);
    int i = bsearch32(E, xc);

    float xk  = E[i],  xk1 = E[i + 1];
    float yk  = Hc[i], yk1 = Hc[i + 1];
    float dk  = Dv[i], dk1 = Dv[i + 1];

    float wk    = xk1 - xk;
    float hk    = yk1 - yk;
    float invw  = __builtin_amdgcn_rcpf(wk);
    float delta = hk * invw;
    float th    = (xc - xk) * invw;
    float omt   = 1.f - th;
    float t1m   = th * omt;
    float th2   = th * th;

    float num    = hk * fmaf(delta, th2, dk * t1m);
    float den    = fmaf(fmaf(-2.f, delta, dk + dk1), t1m, delta);
    float invden = __builtin_amdgcn_rcpf(den);
    float y      = fmaf(num, invden, yk);

    float dt    = delta * t1m;
    float inner = fmaf(dk1, th2, fmaf(dk, omt * omt, dt + dt));
    float dnum  = (delta * delta) * inner;
    float r  = dnum * invden * invden;
    float ld = LN2 * __builtin_amdgcn_logf(r);

    bool inside = (zc >= -TB) && (zc <= TB);
    zo  = inside ? y : zc;
    ldo = inside ? ld : 0.f;
}

// exact chain for one (x, channel) from LDS-staged T
__device__ __forceinline__ void exact_chain(const float* __restrict__ T,
                                            float xv, int c,
                                            float& zout, float& lout) {
    const float* ScT = T + PT_FLOATS;
    const float* BbT = ScT + 72;
    const float* LJT = BbT + 72;
    float zc = xv;
    float lacc = LJT[c];
#pragma unroll 1
    for (int l = 0; l < NL; ++l) {
        zc = (zc - BbT[l * 8 + c]) * ScT[l * 8 + c];
        float ld;
        spline_eval(T + (l * 8 + c) * 99, zc, zc, ld);
        lacc += ld;
    }
    zout = (zc - BbT[NL * 8 + c]) * ScT[NL * 8 + c];
    lout = lacc;
}

// ---------------- kernel 1: build tables once -> gparam ----------------
extern "C" __global__ void __launch_bounds__(256)
build_tables(const float* __restrict__ w, const float* __restrict__ h,
             const float* __restrict__ s, const float* __restrict__ bias,
             const float* __restrict__ lsc, float* __restrict__ gparam)
{
    __shared__ float T[PT_FLOATS];
    __shared__ float Sc[72], Bb[72], LJ[8];

    const int tid = threadIdx.x;

    if (tid < 64) {                       // widths -> cumw edges
        const int l = tid >> 3, c = tid & 7;
        float* cw = &T[tid * 99];
        const float* wr = w + (l * NC + c) * NB;
        float m = wr[0];
        for (int b = 1; b < NB; ++b) m = fmaxf(m, wr[b]);
        float sum = 0.f;
        for (int b = 0; b < NB; ++b) sum += expf(wr[b] - m);
        float inv = 1.f / sum;
        float acc = 0.f;
        cw[0] = -TB;
        for (int b = 0; b < NB; ++b) {
            acc += 1e-3f + (1.f - 1e-3f * NB) * (expf(wr[b] - m) * inv);
            cw[b + 1] = 6.f * acc - 3.f;
        }
        cw[NB] = TB;
    } else if (tid < 128) {               // heights -> cumh
        const int t = tid - 64;
        float* ch = &T[t * 99 + 33];
        const int l = t >> 3, c = t & 7;
        const float* hr = h + (l * NC + c) * NB;
        float m = hr[0];
        for (int b = 1; b < NB; ++b) m = fmaxf(m, hr[b]);
        float sum = 0.f;
        for (int b = 0; b < NB; ++b) sum += expf(hr[b] - m);
        float inv = 1.f / sum;
        float acc = 0.f;
        ch[0] = -TB;
        for (int b = 0; b < NB; ++b) {
            acc += 1e-3f + (1.f - 1e-3f * NB) * (expf(hr[b] - m) * inv);
            ch[b + 1] = 6.f * acc - 3.f;
        }
        ch[NB] = TB;
    } else if (tid < 192) {               // derivs
        const int t = tid - 128;
        const int l = t >> 3, c = t & 7;
        float* dv = &T[t * 99 + 66];
        const float* sr = s + (l * NC + c) * (NB - 1);
        const float cst = logf(expm1f(1.f - 1e-3f));
        const float dbound = 1e-3f + softplusf(cst);
        dv[0]  = dbound;
        dv[NB] = dbound;
        for (int k = 0; k < NB - 1; ++k)
            dv[k + 1] = 1e-3f + softplusf(sr[k]);
    }
    if (tid < 72) { Sc[tid] = expf(-lsc[tid]); Bb[tid] = bias[tid]; }
    if (tid < 8) {
        float a = 0.f;
        for (int l = 0; l <= NL; ++l) a += lsc[l * NC + tid];
        LJ[tid] = -a;
    }
    __syncthreads();

    for (int k = tid; k < PT_FLOATS; k += 256) gparam[k] = T[k];
    if (tid < 72) gparam[PT_FLOATS + tid]       = Sc[tid];
    if (tid < 72) gparam[PT_FLOATS + 72 + tid]  = Bb[tid];
    if (tid < 8)  gparam[PT_FLOATS + 144 + tid] = LJ[tid];
}

// ------- kernel 2: grid eval, 1 thread per grid point (8 ch serial) --------
// Block covers 256 points with 1 overlap: rows [b*255, b*255+254] written.
extern "C" __global__ void __launch_bounds__(256)
grid_eval(const float* __restrict__ gparam, char* __restrict__ tabb,
          int G, float dx)
{
    __shared__ float T[GP_FLOATS];
    __shared__ unsigned short ZL[256 * 16];   // h(z)[8] | h(lj)[8] per thread
    for (int k = threadIdx.x; k < GP_FLOATS; k += 256) T[k] = gparam[k];
    __syncthreads();
    const float* ScT = T + PT_FLOATS;
    const float* BbT = ScT + 72;
    const float* LJT = BbT + 72;

    const int t  = threadIdx.x;
    const int p0 = blockIdx.x * 255;
    const int i  = min(p0 + t, G - 1);

    const float xv = fmaf((float)i, dx, GX0);
    float z[NC], lj[NC];
#pragma unroll
    for (int c = 0; c < NC; ++c) { z[c] = xv; lj[c] = LJT[c]; }

#pragma unroll 1
    for (int l = 0; l < NL; ++l) {
        const float* Tl = T + l * NC * 99;
#pragma unroll
        for (int c = 0; c < NC; ++c) {
            float u = (z[c] - BbT[l * 8 + c]) * ScT[l * 8 + c];
            float zo, ld;
            spline_eval(Tl + c * 99, u, zo, ld);
            z[c] = zo;
            lj[c] += ld;
        }
    }
    unsigned short zh[NC], lh[NC];
#pragma unroll
    for (int c = 0; c < NC; ++c) {
        z[c] = (z[c] - BbT[NL * 8 + c]) * ScT[NL * 8 + c];
        zh[c] = f2h(z[c]);
        lh[c] = f2h(lj[c]);
        ZL[t * 16 + c]     = zh[c];
        ZL[t * 16 + 8 + c] = lh[c];
    }
    __syncthreads();

    const int r = p0 + t;
    if (t < 255 && r <= G - 2) {
        ushort4* rowp = (ushort4*)(tabb + (size_t)r * 64);
#pragma unroll
        for (int c = 0; c < NC; ++c) {
            const float zn  = h2f(ZL[(t + 1) * 16 + c]);
            const float ljn = h2f(ZL[(t + 1) * 16 + 8 + c]);
            ushort4 v;
            v.x = zh[c]; v.y = f2h(zn - h2f(zh[c]));
            v.z = lh[c]; v.w = f2h(ljn - h2f(lh[c]));
            rowp[c] = v;
        }
    }
}

// ------- kernel 3: fused interp8, loads-first schedule ----------------------
// Block covers 256 points. Thread = (pbase=tid>>3, c=tid&7).
// Loop A: issue all 8 uint2 gathers (independent). Loop B: consume, lerp,
// store unflagged, pool flagged into per-wave 64-entry LDS regions (running
// in-register count; no atomics, deterministic). Post-barrier: pool threads
// exact-eval from staged tables and write OUT directly.
extern "C" __global__ void __launch_bounds__(256)
interp_kernel(const float* __restrict__ x, const char* __restrict__ tabb,
              const float* __restrict__ gparam, float* __restrict__ out,
              int N, int G, float dx, float invdx)
{
    __shared__ float T[GP_FLOATS];
    __shared__ float xbuf[256];
    __shared__ unsigned short pool[CAP];
    __shared__ unsigned wcnt_lds[4];

    const int tid   = threadIdx.x;
    const int c     = tid & 7;
    const int pbase = tid >> 3;           // 0..31
    const int lane  = tid & 63;
    const int wloc  = tid >> 6;           // 0..3
    const int P0    = blockIdx.x * 256;

    // ---- loop A: issue all loads (8 independent gathers in flight) ----
    uint2 ab[8];
    float xr[8];
#pragma unroll
    for (int g = 0; g < 8; ++g) {
        const int p = P0 + g * 32 + pbase;
        float xv = 0.f;
        uint2 v; v.x = 0u; v.y = 0u;
        if (p < N) {
            xv = x[p];                    // 8 lanes same addr -> broadcast
            int i = (int)floorf((xv - GX0) * invdx);
            i = min(max(i, 0), G - 2);
            v = *(const uint2*)(tabb + (size_t)i * 64 + c * 8);
        }
        xr[g] = xv;
        ab[g] = v;
        if (c == 0) xbuf[g * 32 + pbase] = xv;
    }

    // ---- loop B: consume, lerp, store unflagged, pool flagged ----
    unsigned cntw = 0;                    // running flagged count in this wave
    unsigned ovf  = 0;                    // per-lane overflow bitmask over g
#pragma unroll
    for (int g = 0; g < 8; ++g) {
        const int p = P0 + g * 32 + pbase;
        const bool active = (p < N);
        bool flag = false;
        float zv = 0.f, lv = 0.f;
        if (active) {
            const float xv = xr[g];
            int i = (int)floorf((xv - GX0) * invdx);
            const bool oor = !(xv > GX0 && xv < GX1);
            i = min(max(i, 0), G - 2);
            const float t  = (xv - fmaf((float)i, dx, GX0)) * invdx;
            const float z0 = h2f((unsigned short)ab[g].x);
            const float dz = h2f((unsigned short)(ab[g].x >> 16));
            const float l0 = h2f((unsigned short)ab[g].y);
            const float dl = h2f((unsigned short)(ab[g].y >> 16));
            zv = fmaf(t, dz, z0);
            lv = fmaf(t, dl, l0);
            flag = oor || (fabsf(dz) > TZ) || (fabsf(dl) > TL);
        }
        const unsigned long long m = __ballot(flag);
        if (flag) {
            const unsigned rank = cntw +
                (unsigned)__popcll(m & ((1ull << lane) - 1ull));
            if (rank < 64u)
                pool[wloc * 64 + rank] =
                    (unsigned short)(((g * 32 + pbase) << 3) | c);
            else
                ovf |= (1u << g);
        }
        cntw += (unsigned)__popcll(m);
        if (active && !flag) {
            out[(size_t)p * NC + c] = zv;                    // 256B/wave contig
            out[(size_t)N * NC + (size_t)p * NC + c] = lv;
        }
    }
    if (lane == 0) wcnt_lds[wloc] = min(cntw, 64u);
    __syncthreads();                      // pool + xbuf + wcnt visible

    const unsigned btot = wcnt_lds[0] + wcnt_lds[1] + wcnt_lds[2] + wcnt_lds[3];
    if (btot > 0) {
        for (int k = tid; k < GP_FLOATS; k += 256) T[k] = gparam[k];
    }
    __syncthreads();                      // T staged

    // pool processing: thread tid handles region tid>>6, entry tid&63
    {
        const unsigned reg = (unsigned)(tid >> 6);
        const unsigned e   = (unsigned)(tid & 63);
        if (e < wcnt_lds[reg]) {
            const unsigned pr = pool[reg * 64 + e];
            const int pl = (int)(pr >> 3), cc = (int)(pr & 7u);
            const int p  = P0 + pl;
            float zo, lo;
            exact_chain(T, xbuf[pl], cc, zo, lo);
            if (p < N) {
                out[(size_t)p * NC + cc] = zo;
                out[(size_t)N * NC + (size_t)p * NC + cc] = lo;
            }
        }
    }

    // overflow (rank>=64 in a wave): owner computes inline from staged T
    if (ovf) {
#pragma unroll 1
        for (int g = 0; g < 8; ++g) {
            if ((ovf >> g) & 1u) {
                const int p = P0 + g * 32 + pbase;
                if (p < N) {
                    float zo, lo;
                    exact_chain(T, xr[g], c, zo, lo);
                    out[(size_t)p * NC + c] = zo;
                    out[(size_t)N * NC + (size_t)p * NC + c] = lo;
                }
            }
        }
    }
}

// ---------------- legacy monolithic kernel (ws-too-small fallback) ----------
extern "C" __global__ void __launch_bounds__(256)
flow_kernel(const float* __restrict__ x, const float* __restrict__ w,
            const float* __restrict__ h, const float* __restrict__ s,
            const float* __restrict__ bias, const float* __restrict__ lsc,
            float* __restrict__ out, int N)
{
    __shared__ float T[PT_FLOATS];
    __shared__ float Bb[NL + 1][NC];
    __shared__ float Sc[NL + 1][NC];
    __shared__ float LJC[NC];

    const int tid = threadIdx.x;
    if (tid < 64) {
        const int l = tid >> 3, c = tid & 7;
        float* cw = &T[tid * 99];
        {
            const float* wr = w + (l * NC + c) * NB;
            float m = wr[0];
            for (int b = 1; b < NB; ++b) m = fmaxf(m, wr[b]);
            float sum = 0.f;
            for (int b = 0; b < NB; ++b) sum += expf(wr[b] - m);
            float inv = 1.f / sum;
            float acc = 0.f;
            cw[0] = -TB;
            for (int b = 0; b < NB; ++b) {
                acc += 1e-3f + (1.f - 1e-3f * NB) * (expf(wr[b] - m) * inv);
                cw[b + 1] = 6.f * acc - 3.f;
            }
            cw[NB] = TB;
        }
        {
            float* ch = cw + 33;
            const float* hr = h + (l * NC + c) * NB;
            float m = hr[0];
            for (int b = 1; b < NB; ++b) m = fmaxf(m, hr[b]);
            float sum = 0.f;
            for (int b = 0; b < NB; ++b) sum += expf(hr[b] - m);
            float inv = 1.f / sum;
            float acc = 0.f;
            ch[0] = -TB;
            for (int b = 0; b < NB; ++b) {
                acc += 1e-3f + (1.f - 1e-3f * NB) * (expf(hr[b] - m) * inv);
                ch[b + 1] = 6.f * acc - 3.f;
            }
            ch[NB] = TB;
        }
        {
            float* dv = cw + 66;
            const float* sr = s + (l * NC + c) * (NB - 1);
            const float cst = logf(expm1f(1.f - 1e-3f));
            const float dbound = 1e-3f + softplusf(cst);
            dv[0]  = dbound;
            dv[NB] = dbound;
            for (int k = 0; k < NB - 1; ++k)
                dv[k + 1] = 1e-3f + softplusf(sr[k]);
        }
    }
    if (tid < (NL + 1) * NC) {
        const int l = tid >> 3, c = tid & 7;
        Bb[l][c] = bias[tid];
        Sc[l][c] = expf(-lsc[tid]);
    }
    if (tid < NC) {
        float a = 0.f;
        for (int l = 0; l <= NL; ++l) a += lsc[l * NC + tid];
        LJC[tid] = -a;
    }
    __syncthreads();

    const int n = blockIdx.x * 256 + tid;
    if (n >= N) return;
    const float xv = x[n];
    float z[NC], lj[NC];
#pragma unroll
    for (int c = 0; c < NC; ++c) { z[c] = xv; lj[c] = LJC[c]; }
#pragma unroll 1
    for (int l = 0; l < NL; ++l) {
        const float* Tl = &T[l * NC * 99];
#pragma unroll
        for (int c = 0; c < NC; ++c) {
            float zc = (z[c] - Bb[l][c]) * Sc[l][c];
            float zo, ld;
            spline_eval(Tl + c * 99, zc, zo, ld);
            z[c] = zo;
            lj[c] += ld;
        }
    }
#pragma unroll
    for (int c = 0; c < NC; ++c) z[c] = (z[c] - Bb[NL][c]) * Sc[NL][c];

    float4* oz = (float4*)(out + (size_t)n * NC);
    oz[0] = make_float4(z[0], z[1], z[2], z[3]);
    oz[1] = make_float4(z[4], z[5], z[6], z[7]);
    float4* ol = (float4*)(out + (size_t)N * NC + (size_t)n * NC);
    ol[0] = make_float4(lj[0], lj[1], lj[2], lj[3]);
    ol[1] = make_float4(lj[4], lj[5], lj[6], lj[7]);
}

extern "C" void kernel_launch(void* const* d_in, const int* in_sizes, int n_in,
                              void* d_out, int out_size, void* d_ws, size_t ws_size,
                              hipStream_t stream) {
    const float* x    = (const float*)d_in[0];
    const float* w    = (const float*)d_in[1];
    const float* h    = (const float*)d_in[2];
    const float* s    = (const float*)d_in[3];
    const float* bias = (const float*)d_in[4];
    const float* lsc  = (const float*)d_in[5];
    float* out = (float*)d_out;
    const int N = in_sizes[0];

    // Layout (bytes): [0,GP_BYTES) gparam | [TAB_OFF,+G*64) packed tab
    int G = 65536;
    while (G > 2048 && ((size_t)TAB_OFF + (size_t)G * 64) > ws_size)
        G >>= 1;
    const size_t need = (size_t)TAB_OFF + (size_t)G * 64;

    if (need <= ws_size) {
        char* basep = (char*)d_ws;
        float* gparam = (float*)basep;
        char*  tabb   = basep + TAB_OFF;

        const float dx = (GX1 - GX0) / (float)(G - 1);
        const int gblocks = (G - 1 + 254) / 255;
        build_tables<<<1, 256, 0, stream>>>(w, h, s, bias, lsc, gparam);
        grid_eval<<<gblocks, 256, 0, stream>>>(gparam, tabb, G, dx);
        interp_kernel<<<(N + 255) / 256, 256, 0, stream>>>(
            x, tabb, gparam, out, N, G, dx, 1.f / dx);
    } else {
        flow_kernel<<<(N + 255) / 256, 256, 0, stream>>>(
            x, w, h, s, bias, lsc, out, N);
    }
}

// Round 17
// 61.918 us; speedup vs baseline: 1.5961x; 1.1859x over previous
//
#include <hip/hip_runtime.h>
#include <hip/hip_bf16.h>

// UnivariateFlowMixture: N=1e6 points, C=8 channels, L=8 layers, B=32 bins.
// Pipeline: build_tables (1 blk) -> grid_eval (2 threads/point, 4ch each,
// LDS f16 neighbor exchange, packed 64B rows) -> interp_fused (1 thread/point
// lerp + per-POINT block pool + in-kernel exact, zero atomics).
// Round 17: revert r14-r16 8-lane experiments (all lost to r13's 63.9us).
// vs r13: grid_eval 2x parallelism (was 1 wave/SIMD at G=65536), interp pool
// per-point (1 ballot not 8, ~30 fewer VALU/point, smaller LDS).

#define TB 3.0f
#define NB 32
#define NC 8
#define NL 8
#define LN2 0.69314718055994530942f

#define GX0 -6.5f
#define GX1 6.5f
#define TZ 0.5f
#define TL 0.5f

#define PT_FLOATS (64 * 99)                  // 6336: 64 tables of 33|33|33
#define GP_FLOATS (PT_FLOATS + 72 + 72 + 8)  // + Sc | Bb | LJ  (6488 floats)
#define GP_BYTES  (GP_FLOATS * 4)            // 25952
#define TAB_OFF   26112                      // 64B-aligned (64*408)
#define CAPP 64                              // pooled points per block

__device__ __forceinline__ float softplusf(float v) {
    return fmaxf(v, 0.f) + log1pf(expf(-fabsf(v)));
}

__device__ __forceinline__ unsigned short f2h(float f) {
    _Float16 h = (_Float16)f;
    unsigned short u;
    __builtin_memcpy(&u, &h, 2);
    return u;
}
__device__ __forceinline__ float h2f(unsigned short u) {
    _Float16 h;
    __builtin_memcpy(&h, &u, 2);
    return (float)h;
}

__device__ __forceinline__ int bsearch32(const float* __restrict__ E, float xc) {
    int i = (xc >= E[16]) ? 16 : 0;
    i += (xc >= E[i + 8]) ? 8 : 0;
    i += (xc >= E[i + 4]) ? 4 : 0;
    i += (xc >= E[i + 2]) ? 2 : 0;
    i += (xc >= E[i + 1]) ? 1 : 0;
    return i;
}

// Tlc: [0..32] cumw edges, [33..65] cumh, [66..98] derivs (LDS or global)
__device__ __forceinline__ void spline_eval(const float* __restrict__ Tlc,
                                            float zc, float& zo, float& ldo) {
    const float* E  = Tlc;
    const float* Hc = Tlc + 33;
    const float* Dv = Tlc + 66;

    float xc = fminf(fmaxf(zc, -TB), TB);
    int i = bsearch32(E, xc);

    float xk  = E[i],  xk1 = E[i + 1];
    float yk  = Hc[i], yk1 = Hc[i + 1];
    float dk  = Dv[i], dk1 = Dv[i + 1];

    float wk    = xk1 - xk;
    float hk    = yk1 - yk;
    float invw  = __builtin_amdgcn_rcpf(wk);
    float delta = hk * invw;
    float th    = (xc - xk) * invw;
    float omt   = 1.f - th;
    float t1m   = th * omt;
    float th2   = th * th;

    float num    = hk * fmaf(delta, th2, dk * t1m);
    float den    = fmaf(fmaf(-2.f, delta, dk + dk1), t1m, delta);
    float invden = __builtin_amdgcn_rcpf(den);
    float y      = fmaf(num, invden, yk);

    float dt    = delta * t1m;
    float inner = fmaf(dk1, th2, fmaf(dk, omt * omt, dt + dt));
    float dnum  = (delta * delta) * inner;
    float r  = dnum * invden * invden;
    float ld = LN2 * __builtin_amdgcn_logf(r);

    bool inside = (zc >= -TB) && (zc <= TB);
    zo  = inside ? y : zc;
    ldo = inside ? ld : 0.f;
}

// exact chain for one (x, channel) from LDS-staged T
__device__ __forceinline__ void exact_chain(const float* __restrict__ T,
                                            float xv, int c,
                                            float& zout, float& lout) {
    const float* ScT = T + PT_FLOATS;
    const float* BbT = ScT + 72;
    const float* LJT = BbT + 72;
    float zc = xv;
    float lacc = LJT[c];
#pragma unroll 1
    for (int l = 0; l < NL; ++l) {
        zc = (zc - BbT[l * 8 + c]) * ScT[l * 8 + c];
        float ld;
        spline_eval(T + (l * 8 + c) * 99, zc, zc, ld);
        lacc += ld;
    }
    zout = (zc - BbT[NL * 8 + c]) * ScT[NL * 8 + c];
    lout = lacc;
}

// ---------------- kernel 1: build tables once -> gparam ----------------
extern "C" __global__ void __launch_bounds__(256)
build_tables(const float* __restrict__ w, const float* __restrict__ h,
             const float* __restrict__ s, const float* __restrict__ bias,
             const float* __restrict__ lsc, float* __restrict__ gparam)
{
    __shared__ float T[PT_FLOATS];
    __shared__ float Sc[72], Bb[72], LJ[8];

    const int tid = threadIdx.x;

    if (tid < 64) {                       // widths -> cumw edges
        const int l = tid >> 3, c = tid & 7;
        float* cw = &T[tid * 99];
        const float* wr = w + (l * NC + c) * NB;
        float m = wr[0];
        for (int b = 1; b < NB; ++b) m = fmaxf(m, wr[b]);
        float sum = 0.f;
        for (int b = 0; b < NB; ++b) sum += expf(wr[b] - m);
        float inv = 1.f / sum;
        float acc = 0.f;
        cw[0] = -TB;
        for (int b = 0; b < NB; ++b) {
            acc += 1e-3f + (1.f - 1e-3f * NB) * (expf(wr[b] - m) * inv);
            cw[b + 1] = 6.f * acc - 3.f;
        }
        cw[NB] = TB;
    } else if (tid < 128) {               // heights -> cumh
        const int t = tid - 64;
        float* ch = &T[t * 99 + 33];
        const int l = t >> 3, c = t & 7;
        const float* hr = h + (l * NC + c) * NB;
        float m = hr[0];
        for (int b = 1; b < NB; ++b) m = fmaxf(m, hr[b]);
        float sum = 0.f;
        for (int b = 0; b < NB; ++b) sum += expf(hr[b] - m);
        float inv = 1.f / sum;
        float acc = 0.f;
        ch[0] = -TB;
        for (int b = 0; b < NB; ++b) {
            acc += 1e-3f + (1.f - 1e-3f * NB) * (expf(hr[b] - m) * inv);
            ch[b + 1] = 6.f * acc - 3.f;
        }
        ch[NB] = TB;
    } else if (tid < 192) {               // derivs
        const int t = tid - 128;
        const int l = t >> 3, c = t & 7;
        float* dv = &T[t * 99 + 66];
        const float* sr = s + (l * NC + c) * (NB - 1);
        const float cst = logf(expm1f(1.f - 1e-3f));
        const float dbound = 1e-3f + softplusf(cst);
        dv[0]  = dbound;
        dv[NB] = dbound;
        for (int k = 0; k < NB - 1; ++k)
            dv[k + 1] = 1e-3f + softplusf(sr[k]);
    }
    if (tid < 72) { Sc[tid] = expf(-lsc[tid]); Bb[tid] = bias[tid]; }
    if (tid < 8) {
        float a = 0.f;
        for (int l = 0; l <= NL; ++l) a += lsc[l * NC + tid];
        LJ[tid] = -a;
    }
    __syncthreads();

    for (int k = tid; k < PT_FLOATS; k += 256) gparam[k] = T[k];
    if (tid < 72) gparam[PT_FLOATS + tid]       = Sc[tid];
    if (tid < 72) gparam[PT_FLOATS + 72 + tid]  = Bb[tid];
    if (tid < 8)  gparam[PT_FLOATS + 144 + tid] = LJ[tid];
}

// ------- kernel 2: grid eval, 2 threads/point (4 channels each) ------------
// Block covers 128 points with 1 overlap: rows [b*127, b*127+126] written.
// thread: pl = tid&127, c0 = (tid>>7)*4. Neighbor exchange via f16 LDS.
extern "C" __global__ void __launch_bounds__(256)
grid_eval(const float* __restrict__ gparam, char* __restrict__ tabb,
          int G, float dx)
{
    __shared__ float T[GP_FLOATS];
    __shared__ unsigned short ZL[128 * 16];   // h(z)[8] | h(lj)[8] per point
    for (int k = threadIdx.x; k < GP_FLOATS; k += 256) T[k] = gparam[k];
    __syncthreads();
    const float* ScT = T + PT_FLOATS;
    const float* BbT = ScT + 72;
    const float* LJT = BbT + 72;

    const int pl = threadIdx.x & 127;
    const int c0 = (threadIdx.x >> 7) * 4;    // 0 or 4
    const int p0 = blockIdx.x * 127;
    const int i  = min(p0 + pl, G - 1);

    const float xv = fmaf((float)i, dx, GX0);
    float z[4], lj[4];
#pragma unroll
    for (int cc = 0; cc < 4; ++cc) { z[cc] = xv; lj[cc] = LJT[c0 + cc]; }

#pragma unroll 1
    for (int l = 0; l < NL; ++l) {
        const float* Tl = T + l * NC * 99;
#pragma unroll
        for (int cc = 0; cc < 4; ++cc) {
            const int c = c0 + cc;
            float u = (z[cc] - BbT[l * 8 + c]) * ScT[l * 8 + c];
            float zo, ld;
            spline_eval(Tl + c * 99, u, zo, ld);
            z[cc] = zo;
            lj[cc] += ld;
        }
    }
    unsigned short zh[4], lh[4];
#pragma unroll
    for (int cc = 0; cc < 4; ++cc) {
        const int c = c0 + cc;
        z[cc] = (z[cc] - BbT[NL * 8 + c]) * ScT[NL * 8 + c];
        zh[cc] = f2h(z[cc]);
        lh[cc] = f2h(lj[cc]);
        ZL[pl * 16 + c]     = zh[cc];
        ZL[pl * 16 + 8 + c] = lh[cc];
    }
    __syncthreads();

    const int r = p0 + pl;
    if (pl < 127 && r <= G - 2) {
        ushort4* rowp = (ushort4*)(tabb + (size_t)r * 64);
#pragma unroll
        for (int cc = 0; cc < 4; ++cc) {
            const int c = c0 + cc;
            const float zn  = h2f(ZL[(pl + 1) * 16 + c]);
            const float ljn = h2f(ZL[(pl + 1) * 16 + 8 + c]);
            ushort4 v;
            v.x = zh[cc]; v.y = f2h(zn - h2f(zh[cc]));
            v.z = lh[cc]; v.w = f2h(ljn - h2f(lh[cc]));
            rowp[c] = v;
        }
    }
}

// ------- kernel 3: fused interp (1 thread/point) + per-POINT pool -----------
extern "C" __global__ void __launch_bounds__(256)
interp_kernel(const float* __restrict__ x, const char* __restrict__ tabb,
              const float* __restrict__ gparam, float* __restrict__ out,
              int N, int G, float dx, float invdx)
{
    __shared__ float T[GP_FLOATS];
    __shared__ float xbuf[256];
    __shared__ unsigned char pool[CAPP];
    __shared__ float resZ[CAPP * 8], resL[CAPP * 8];
    __shared__ unsigned wcnt[4];

    const int tid  = threadIdx.x;
    const int n    = blockIdx.x * 256 + tid;
    const int lane = tid & 63;
    const int wloc = tid >> 6;
    const bool active = (n < N);

    float xv = 0.f;
    if (active) xv = x[n];
    xbuf[tid] = xv;

    float z[NC], lj[NC];
    bool pflag = false;
    if (active) {
        int i = (int)floorf((xv - GX0) * invdx);
        const bool oor = !(xv > GX0 && xv < GX1);
        i = min(max(i, 0), G - 2);
        const float t = (xv - fmaf((float)i, dx, GX0)) * invdx;

        const float4* rp = (const float4*)(tabb + (size_t)i * 64);
        union { float4 q[4]; unsigned int u[16]; } R;
        R.q[0] = rp[0]; R.q[1] = rp[1]; R.q[2] = rp[2]; R.q[3] = rp[3];
        int flags = 0;
#pragma unroll
        for (int c = 0; c < NC; ++c) {
            const unsigned a = R.u[2 * c], b = R.u[2 * c + 1];
            const float z0 = h2f((unsigned short)a);
            const float dz = h2f((unsigned short)(a >> 16));
            const float l0 = h2f((unsigned short)b);
            const float dl = h2f((unsigned short)(b >> 16));
            z[c]  = fmaf(t, dz, z0);
            lj[c] = fmaf(t, dl, l0);
            if (fabsf(dz) > TZ || fabsf(dl) > TL) flags = 1;
        }
        pflag = oor || (flags != 0);
    }

    // per-point pooling: one ballot, deterministic, no atomics
    const unsigned long long m = __ballot(pflag);
    if (lane == 0) wcnt[wloc] = (unsigned)__popcll(m);
    __syncthreads();                      // wcnt + xbuf visible

    unsigned woff = 0, btot = 0;
#pragma unroll
    for (int j = 0; j < 4; ++j) {
        const unsigned v = wcnt[j];
        if (j < wloc) woff += v;
        btot += v;
    }
    const unsigned idx = woff +
        (unsigned)__popcll(m & ((1ull << lane) - 1ull));
    if (pflag && idx < CAPP) pool[idx] = (unsigned char)tid;
    if (btot > 0) {                       // stage tables only when needed
        for (int k = tid; k < GP_FLOATS; k += 256) T[k] = gparam[k];
    }
    __syncthreads();                      // pool + T visible

    const unsigned pcnt = min(btot, (unsigned)CAPP);
    for (unsigned k = tid; k < pcnt * 8u; k += 256) {
        const int pt = (int)pool[k >> 3];
        const int cc = (int)(k & 7u);
        float zo, lo;
        exact_chain(T, xbuf[pt], cc, zo, lo);
        resZ[k] = zo; resL[k] = lo;
    }
    __syncthreads();                      // results visible

    if (pflag) {
        if (idx < CAPP) {
#pragma unroll
            for (int c = 0; c < NC; ++c) {
                z[c]  = resZ[idx * 8 + c];
                lj[c] = resL[idx * 8 + c];
            }
        } else {                          // pool overflow: inline exact
#pragma unroll 1
            for (int c = 0; c < NC; ++c)
                exact_chain(T, xv, c, z[c], lj[c]);
        }
    }

    if (active) {
        float4* oz = (float4*)(out + (size_t)n * NC);
        oz[0] = make_float4(z[0], z[1], z[2], z[3]);
        oz[1] = make_float4(z[4], z[5], z[6], z[7]);
        float4* ol = (float4*)(out + (size_t)N * NC + (size_t)n * NC);
        ol[0] = make_float4(lj[0], lj[1], lj[2], lj[3]);
        ol[1] = make_float4(lj[4], lj[5], lj[6], lj[7]);
    }
}

// ---------------- legacy monolithic kernel (ws-too-small fallback) ----------
extern "C" __global__ void __launch_bounds__(256)
flow_kernel(const float* __restrict__ x, const float* __restrict__ w,
            const float* __restrict__ h, const float* __restrict__ s,
            const float* __restrict__ bias, const float* __restrict__ lsc,
            float* __restrict__ out, int N)
{
    __shared__ float T[PT_FLOATS];
    __shared__ float Bb[NL + 1][NC];
    __shared__ float Sc[NL + 1][NC];
    __shared__ float LJC[NC];

    const int tid = threadIdx.x;
    if (tid < 64) {
        const int l = tid >> 3, c = tid & 7;
        float* cw = &T[tid * 99];
        {
            const float* wr = w + (l * NC + c) * NB;
            float m = wr[0];
            for (int b = 1; b < NB; ++b) m = fmaxf(m, wr[b]);
            float sum = 0.f;
            for (int b = 0; b < NB; ++b) sum += expf(wr[b] - m);
            float inv = 1.f / sum;
            float acc = 0.f;
            cw[0] = -TB;
            for (int b = 0; b < NB; ++b) {
                acc += 1e-3f + (1.f - 1e-3f * NB) * (expf(wr[b] - m) * inv);
                cw[b + 1] = 6.f * acc - 3.f;
            }
            cw[NB] = TB;
        }
        {
            float* ch = cw + 33;
            const float* hr = h + (l * NC + c) * NB;
            float m = hr[0];
            for (int b = 1; b < NB; ++b) m = fmaxf(m, hr[b]);
            float sum = 0.f;
            for (int b = 0; b < NB; ++b) sum += expf(hr[b] - m);
            float inv = 1.f / sum;
            float acc = 0.f;
            ch[0] = -TB;
            for (int b = 0; b < NB; ++b) {
                acc += 1e-3f + (1.f - 1e-3f * NB) * (expf(hr[b] - m) * inv);
                ch[b + 1] = 6.f * acc - 3.f;
            }
            ch[NB] = TB;
        }
        {
            float* dv = cw + 66;
            const float* sr = s + (l * NC + c) * (NB - 1);
            const float cst = logf(expm1f(1.f - 1e-3f));
            const float dbound = 1e-3f + softplusf(cst);
            dv[0]  = dbound;
            dv[NB] = dbound;
            for (int k = 0; k < NB - 1; ++k)
                dv[k + 1] = 1e-3f + softplusf(sr[k]);
        }
    }
    if (tid < (NL + 1) * NC) {
        const int l = tid >> 3, c = tid & 7;
        Bb[l][c] = bias[tid];
        Sc[l][c] = expf(-lsc[tid]);
    }
    if (tid < NC) {
        float a = 0.f;
        for (int l = 0; l <= NL; ++l) a += lsc[l * NC + tid];
        LJC[tid] = -a;
    }
    __syncthreads();

    const int n = blockIdx.x * 256 + tid;
    if (n >= N) return;
    const float xv = x[n];
    float z[NC], lj[NC];
#pragma unroll
    for (int c = 0; c < NC; ++c) { z[c] = xv; lj[c] = LJC[c]; }
#pragma unroll 1
    for (int l = 0; l < NL; ++l) {
        const float* Tl = &T[l * NC * 99];
#pragma unroll
        for (int c = 0; c < NC; ++c) {
            float zc = (z[c] - Bb[l][c]) * Sc[l][c];
            float zo, ld;
            spline_eval(Tl + c * 99, zc, zo, ld);
            z[c] = zo;
            lj[c] += ld;
        }
    }
#pragma unroll
    for (int c = 0; c < NC; ++c) z[c] = (z[c] - Bb[NL][c]) * Sc[NL][c];

    float4* oz = (float4*)(out + (size_t)n * NC);
    oz[0] = make_float4(z[0], z[1], z[2], z[3]);
    oz[1] = make_float4(z[4], z[5], z[6], z[7]);
    float4* ol = (float4*)(out + (size_t)N * NC + (size_t)n * NC);
    ol[0] = make_float4(lj[0], lj[1], lj[2], lj[3]);
    ol[1] = make_float4(lj[4], lj[5], lj[6], lj[7]);
}

extern "C" void kernel_launch(void* const* d_in, const int* in_sizes, int n_in,
                              void* d_out, int out_size, void* d_ws, size_t ws_size,
                              hipStream_t stream) {
    const float* x    = (const float*)d_in[0];
    const float* w    = (const float*)d_in[1];
    const float* h    = (const float*)d_in[2];
    const float* s    = (const float*)d_in[3];
    const float* bias = (const float*)d_in[4];
    const float* lsc  = (const float*)d_in[5];
    float* out = (float*)d_out;
    const int N = in_sizes[0];

    // Layout (bytes): [0,GP_BYTES) gparam | [TAB_OFF,+G*64) packed tab
    int G = 65536;
    while (G > 2048 && ((size_t)TAB_OFF + (size_t)G * 64) > ws_size)
        G >>= 1;
    const size_t need = (size_t)TAB_OFF + (size_t)G * 64;

    if (need <= ws_size) {
        char* basep = (char*)d_ws;
        float* gparam = (float*)basep;
        char*  tabb   = basep + TAB_OFF;

        const float dx = (GX1 - GX0) / (float)(G - 1);
        const int gblocks = (G - 1 + 126) / 127;
        build_tables<<<1, 256, 0, stream>>>(w, h, s, bias, lsc, gparam);
        grid_eval<<<gblocks, 256, 0, stream>>>(gparam, tabb, G, dx);
        interp_kernel<<<(N + 255) / 256, 256, 0, stream>>>(
            x, tabb, gparam, out, N, G, dx, 1.f / dx);
    } else {
        flow_kernel<<<(N + 255) / 256, 256, 0, stream>>>(
            x, w, h, s, bias, lsc, out, N);
    }
}